// Round 6
// baseline (2377.810 us; speedup 1.0000x reference)
//
#include <hip/hip_runtime.h>
#include <hip/hip_bf16.h>
#include <hip/hip_fp16.h>
#include <stdint.h>

#define TLEN 512
#define TC 64
#define NCH (TLEN/TC)

typedef unsigned short u16;
typedef unsigned int u32;

__device__ __forceinline__ float b2f(u16 u){ union{u32 i; float f;} v; v.i = ((u32)u)<<16; return v.f; }
__device__ __forceinline__ u16 f2bf(float f){
    union{float f; u32 i;} v; v.f = f;
    u32 b = v.i; b += 0x7fffu + ((b>>16)&1u);   // RNE
    return (u16)(b>>16);
}
__device__ __forceinline__ float fexp2(float x){ return __builtin_amdgcn_exp2f(x); }
__device__ __forceinline__ float frcp(float x){ return __builtin_amdgcn_rcpf(x); }
#define LOG2E 1.4426950408889634f
__device__ __forceinline__ float elu_f(float x){ return x > 0.f ? x : fexp2(x*LOG2E) - 1.f; }
__device__ __forceinline__ float sigm(float x){ return frcp(1.f + fexp2(-LOG2E*x)); }
__device__ __forceinline__ float tanh_f(float x){ return 1.f - 2.f*frcp(1.f + fexp2((2.f*LOG2E)*x)); }

// dtype-adaptive load: F=true -> float32 buffer, else bf16 buffer
__device__ __forceinline__ float ldg(const void* p, int i, bool F){
    return F ? ((const float*)p)[i] : b2f(((const u16*)p)[i]);
}

__device__ void fill(float* dst, const void* src, int n, int tid, int nt, bool F){
    for (int i = tid; i < n; i += nt) dst[i] = ldg(src, i, F);
}
__device__ void fillS(float* dst, const void* src, int R, int C, int stride, int tid, int nt, bool F){
    for (int i = tid; i < R*C; i += nt){ int r = i / C, c = i % C; dst[i] = ldg(src, r*stride + c, F); }
}
// transposed: dst[i*K+k] = src[k*stride+i]
__device__ void fillT(float* dst, const void* src, int K, int I, int stride, int tid, int nt, bool F){
    for (int idx = tid; idx < K*I; idx += nt){ int i = idx / K, k = idx % K; dst[idx] = ldg(src, k*stride + i, F); }
}

__global__ __launch_bounds__(256,1) void fused(
    const void* envs, const void* states,
    const void* se_W0, const void* se_b0, const void* se_Wh, const void* se_bh, const void* se_Wo, const void* se_bo,
    const void* oe_W0, const void* oe_b0, const void* oe_Wh, const void* oe_bh, const void* oe_Wo, const void* oe_bo,
    const void* null_embed, const void* init_h,
    const void* att_W0, const void* att_b0, const void* att_Wh, const void* att_bh, const void* att_Wo, const void* att_bo,
    const void* gru0_Wi, const void* gru0_Wh, const void* gru0_bi, const void* gru0_bh,
    const void* gru1_Wi, const void* gru1_Wh, const void* gru1_bi, const void* gru1_bh,
    const void* rel_W0, const void* rel_b0, const void* rel_Wh, const void* rel_bh, const void* rel_Wo, const void* rel_bo,
    const void* fin_W0, const void* fin_b0, const void* fin_Wh, const void* fin_bh, const void* fin_Wo, const void* fin_bo,
    void* out)
{
    // persistent LDS
    __shared__ float sW0T[64], sb0[16], sWhT[768], sbh[48], sWoT[256], sbo[16];
    __shared__ float aW0T[256], aWhT[512], abh[32], aWo[16], abo_s[1];
    __shared__ float wi0se[768];
    __shared__ float rW0T[896], rWhT[448], rbh[56], rWoT[448], rbo[56];
    __shared__ float fW0T[288], fb0[4], fWhT[16], fbh[4], fWoT[16], fbo[4];
    __shared__ float E_att[448], E_rel[224], base_xi[192];
    __shared__ float uni[9088];         // union: phase-0 one-time buffers, then chunk buffers
    __shared__ int s_isf32;

    const int tid = threadIdx.x, nt = 256;
    const int blk = blockIdx.x;

    // ---------------- dtype detection (uniform, deterministic) ----------------
    if (tid == 0){
        // se_W0 has 64 elements. If bf16: even-indexed u16s are real weights
        // (~N(0,0.01)) => |v| in (1e-12,16). If f32: they are low mantissa
        // halves => effectively random 16-bit patterns (p ~ 7e-7 to pass all 8).
        const u16* p = (const u16*)se_W0;
        int ok = 1;
        #pragma unroll
        for (int k = 0; k < 8; k++){
            float v = fabsf(b2f(p[2*k]));
            ok &= (v > 1e-12f && v < 16.f) ? 1 : 0;
        }
        s_isf32 = ok ? 0 : 1;
    }
    __syncthreads();
    const bool F = (s_isf32 != 0);

    // ---------------- phase 0a: stage weights ----------------
    fillT(sW0T, se_W0, 4, 16, 16, tid, nt, F);
    fill (sb0, se_b0, 16, tid, nt, F);
    for (int l = 0; l < 3; l++) fillT(sWhT + l*256, (const u16*)se_Wh + (F?l*512:l*256), 16, 16, 16, tid, nt, F);
    fill (sbh, se_bh, 48, tid, nt, F);
    fillT(sWoT, se_Wo, 16, 16, 16, tid, nt, F);
    fill (sbo, se_bo, 16, tid, nt, F);
    fillT(aW0T, att_W0, 16, 16, 16, tid, nt, F);                 // se rows 0..15
    for (int l = 0; l < 2; l++) fillT(aWhT + l*256, (const u16*)att_Wh + (F?l*512:l*256), 16, 16, 16, tid, nt, F);
    fill (abh, att_bh, 32, tid, nt, F);
    fill (aWo, att_Wo, 16, tid, nt, F);
    fill (abo_s, att_bo, 1, tid, nt, F);
    fillS(wi0se, gru0_Wi, 48, 16, 128, tid, nt, F);              // se cols of Wi0
    for (int s = 0; s < 7; s++){
        fillT(rW0T + s*128, (const u16*)rel_W0 + (F?s*512:s*256), 16, 8, 8, tid, nt, F);   // gru rows 0..15
        fillT(rWhT + s*64, (const u16*)rel_Wh + (F?s*128:s*64), 8, 8, 8, tid, nt, F);
        fillT(rWoT + s*64, (const u16*)rel_Wo + (F?s*128:s*64), 8, 8, 8, tid, nt, F);
    }
    fill (rbh, rel_bh, 56, tid, nt, F);
    fill (rbo, rel_bo, 56, tid, nt, F);
    fillT(fW0T, fin_W0, 72, 4, 4, tid, nt, F);
    fill (fb0, fin_b0, 4, tid, nt, F);
    fillT(fWhT, fin_Wh, 4, 4, 4, tid, nt, F);
    fill (fbh, fin_bh, 4, tid, nt, F);
    fillT(fWoT, fin_Wo, 4, 4, 4, tid, nt, F);
    fill (fbo, fin_bo, 4, tid, nt, F);
    // one-time buffers inside uni
    float* oeW0T = uni;         // 144
    float* oeb0  = uni + 144;   // 48
    float* oeWhT = uni + 192;   // 2304
    float* oebh  = uni + 2496;  // 144
    float* oeWoT = uni + 2640;  // 768
    float* oebo  = uni + 3408;  // 48
    float* aW0To = uni + 3456;  // 256
    float* ab0   = uni + 3712;  // 16
    float* rW0To = uni + 3728;  // 896
    float* objE  = uni + 4624;  // 448
    for (int s = 0; s < 3; s++){
        fillT(oeW0T + s*48, (const u16*)oe_W0 + (F?s*96:s*48), 3, 16, 16, tid, nt, F);
        for (int l = 0; l < 3; l++)
            fillT(oeWhT + (s*3+l)*256, (const u16*)oe_Wh + (F?(s*3+l)*512:(s*3+l)*256), 16, 16, 16, tid, nt, F);
        fillT(oeWoT + s*256, (const u16*)oe_Wo + (F?s*512:s*256), 16, 16, 16, tid, nt, F);
    }
    fill(oeb0, oe_b0, 48, tid, nt, F);
    fill(oebh, oe_bh, 144, tid, nt, F);
    fill(oebo, oe_bo, 48, tid, nt, F);
    fillT(aW0To, (const u16*)att_W0 + (F?512:256), 16, 16, 16, tid, nt, F);  // obj rows 16..31
    fill (ab0, att_b0, 16, tid, nt, F);
    for (int s = 0; s < 7; s++)
        fillT(rW0To + s*128, (const u16*)rel_W0 + (F?(s*512+256):(s*256+128)), 16, 8, 8, tid, nt, F);  // obj rows
    __syncthreads();

    // ---------------- phase 0b: obj embeddings (28 units) ----------------
    if (tid < 28){
        int b1 = tid / 7, s = tid % 7;
        float o[16];
        if (s < 3){
            int b = blk*4 + b1;
            float x0 = ldg(envs, b*9+3*s, F), x1 = ldg(envs, b*9+3*s+1, F), x2 = ldg(envs, b*9+3*s+2, F);
            float h[16], h2[16];
            #pragma unroll
            for (int i = 0; i < 16; i++){
                float a = oeb0[s*16+i] + x0*oeW0T[s*48+i*3] + x1*oeW0T[s*48+i*3+1] + x2*oeW0T[s*48+i*3+2];
                h[i] = elu_f(a);
            }
            for (int l = 0; l < 3; l++){
                #pragma unroll
                for (int i = 0; i < 16; i++){
                    float a = oebh[(s*3+l)*16+i];
                    #pragma unroll
                    for (int k = 0; k < 16; k++) a += h[k]*oeWhT[((s*3+l)*16+i)*16+k];
                    h2[i] = elu_f(a);
                }
                #pragma unroll
                for (int i = 0; i < 16; i++) h[i] = h2[i];
            }
            #pragma unroll
            for (int i = 0; i < 16; i++){
                float a = oebo[s*16+i];
                #pragma unroll
                for (int k = 0; k < 16; k++) a += h[k]*oeWoT[(s*16+i)*16+k];
                o[i] = a;                       // linear output layer
            }
        } else {
            #pragma unroll
            for (int i = 0; i < 16; i++) o[i] = ldg(null_embed, (s-3)*16 + i, F);
        }
        #pragma unroll
        for (int i = 0; i < 16; i++) objE[(b1*7+s)*16 + i] = o[i];
    }
    __syncthreads();

    // ---------------- phase 0c: E_att, E_rel, base_xi ----------------
    for (int idx = tid; idx < 448; idx += nt){
        int r = idx % 112, i = r % 16;
        int os = (idx / 16) * 16;
        float a = ab0[i];
        #pragma unroll
        for (int k = 0; k < 16; k++) a += objE[os + k]*aW0To[i*16+k];
        E_att[idx] = a;
    }
    for (int idx = tid; idx < 224; idx += nt){
        int r = idx % 56, s = r / 8, i = r % 8;
        int b1 = idx / 56;
        float a = ldg(rel_b0, s*8+i, F);
        #pragma unroll
        for (int k = 0; k < 16; k++) a += objE[(b1*7+s)*16 + k]*rW0To[(s*8+i)*16+k];
        E_rel[idx] = a;
    }
    for (int idx = tid; idx < 192; idx += nt){
        int b1 = idx / 48, g = idx % 48;
        float a = ldg(gru0_bi, g, F) + (g < 32 ? ldg(gru0_bh, g, F) : 0.f);
        for (int s = 0; s < 7; s++){
            int wb = g*128 + 16 + s*16;
            #pragma unroll
            for (int k = 0; k < 16; k++) a += objE[(b1*7+s)*16 + k]*ldg(gru0_Wi, wb+k, F);
        }
        base_xi[idx] = a;
    }

    // ---------------- scan weights -> wave-0 registers ----------------
    float w0r[16],w0z[16],w0n[16],wi1r[16],wi1z[16],wi1n[16],wh1r[16],wh1z[16],wh1n[16];
    float h0[16], h1[16];
    float c_hn0=0.f,c_r1=0.f,c_z1=0.f,c_xn1=0.f,c_hn1=0.f,hs0=0.f,hs1=0.f;
    if (tid < 64){
        int j = tid & 15;
        #pragma unroll
        for (int k = 0; k < 16; k++){
            w0r[k]  = ldg(gru0_Wh, j*16+k, F);
            w0z[k]  = ldg(gru0_Wh, (16+j)*16+k, F);
            w0n[k]  = ldg(gru0_Wh, (32+j)*16+k, F);
            wi1r[k] = ldg(gru1_Wi, j*16+k, F);
            wi1z[k] = ldg(gru1_Wi, (16+j)*16+k, F);
            wi1n[k] = ldg(gru1_Wi, (32+j)*16+k, F);
            wh1r[k] = ldg(gru1_Wh, j*16+k, F);
            wh1z[k] = ldg(gru1_Wh, (16+j)*16+k, F);
            wh1n[k] = ldg(gru1_Wh, (32+j)*16+k, F);
        }
        c_hn0 = ldg(gru0_bh, 32+j, F);
        c_r1  = ldg(gru1_bi, j, F)    + ldg(gru1_bh, j, F);
        c_z1  = ldg(gru1_bi, 16+j, F) + ldg(gru1_bh, 16+j, F);
        c_xn1 = ldg(gru1_bi, 32+j, F);
        c_hn1 = ldg(gru1_bh, 32+j, F);
        #pragma unroll
        for (int k = 0; k < 16; k++){ h0[k] = ldg(init_h, k, F); h1[k] = ldg(init_h, 16+k, F); }
        hs0 = ldg(init_h, tid & 15, F);
        hs1 = ldg(init_h, 16 + (tid & 15), F);
    }
    __syncthreads();   // one-time uni region dead -> reuse as chunk buffers

    _Float16* xi_h  = (_Float16*)uni;            // 4b x 64t x 48
    _Float16* gru_h = (_Float16*)(uni + 6144);   // 4b x 64t x 16
    _Float16* csc_h = (_Float16*)(uni + 8192);   // 4b x 7s x 64t

    const int b1p = tid >> 6, tl = tid & 63;
    const int bb = blk*4 + b1p;

    for (int c = 0; c < NCH; c++){
        const int t0 = c*TC;
        // ---------------- phase 1: xi + colsc for chunk ----------------
        {
            const int t = t0 + tl;
            int sbase = ((int)bb*TLEN + t)*4;    // states (B,T,4)
            float x0 = ldg(states, sbase+0, F), x1 = ldg(states, sbase+1, F);
            float x2 = ldg(states, sbase+2, F), x3 = ldg(states, sbase+3, F);
            float h[16], h2[16];
            #pragma unroll
            for (int i = 0; i < 16; i++){
                float a = sb0[i] + x0*sW0T[i*4] + x1*sW0T[i*4+1] + x2*sW0T[i*4+2] + x3*sW0T[i*4+3];
                h[i] = fmaxf(a, 0.f);
            }
            for (int l = 0; l < 3; l++){
                #pragma unroll
                for (int i = 0; i < 16; i++){
                    float a = sbh[l*16+i];
                    #pragma unroll
                    for (int k = 0; k < 16; k++) a += h[k]*sWhT[(l*16+i)*16+k];
                    h2[i] = fmaxf(a, 0.f);
                }
                #pragma unroll
                for (int i = 0; i < 16; i++) h[i] = h2[i];
            }
            float se[16];
            #pragma unroll
            for (int i = 0; i < 16; i++){
                float a = sbo[i];
                #pragma unroll
                for (int k = 0; k < 16; k++) a += h[k]*sWoT[i*16+k];
                se[i] = a;
            }
            float satt[16];
            #pragma unroll
            for (int i = 0; i < 16; i++){
                float a = 0.f;
                #pragma unroll
                for (int k = 0; k < 16; k++) a += se[k]*aW0T[i*16+k];
                satt[i] = a;
            }
            float sc[7];
            for (int s = 0; s < 7; s++){
                const float* ep = E_att + (b1p*7+s)*16;   // includes att_b0
                float a1[16], a2[16];
                #pragma unroll
                for (int i = 0; i < 16; i++) a1[i] = elu_f(satt[i] + ep[i]);
                #pragma unroll
                for (int i = 0; i < 16; i++){
                    float a = abh[i];
                    #pragma unroll
                    for (int k = 0; k < 16; k++) a += a1[k]*aWhT[i*16+k];
                    a2[i] = elu_f(a);
                }
                #pragma unroll
                for (int i = 0; i < 16; i++){
                    float a = abh[16+i];
                    #pragma unroll
                    for (int k = 0; k < 16; k++) a += a2[k]*aWhT[256 + i*16+k];
                    a1[i] = elu_f(a);
                }
                float a = abo_s[0];
                #pragma unroll
                for (int k = 0; k < 16; k++) a += a1[k]*aWo[k];
                sc[s] = a;
            }
            float m = sc[0];
            #pragma unroll
            for (int s = 1; s < 7; s++) m = fmaxf(m, sc[s]);
            float e[7], sum = 0.f;
            #pragma unroll
            for (int s = 0; s < 7; s++){ e[s] = fexp2((sc[s]-m)*LOG2E); sum += e[s]; }
            float inv = frcp(sum);
            #pragma unroll
            for (int s = 0; s < 7; s++)
                csc_h[(b1p*7+s)*64 + tl] = (_Float16)(e[6-s]*inv);   // flip+softmax
            #pragma unroll
            for (int g = 0; g < 48; g++){
                float a = base_xi[b1p*48 + g];
                #pragma unroll
                for (int k = 0; k < 16; k++) a += se[k]*wi0se[g*16+k];
                xi_h[(b1p*64 + tl)*48 + g] = (_Float16)a;
            }
        }
        __syncthreads();
        // ---------------- phase 2: GRU scan (wave 0 only) ----------------
        if (tid < 64){
            const int j = tid & 15, base = tid & 48, b2 = tid >> 4;
            for (int s = 0; s < TC; s++){
                const int sb = (b2*64 + s)*48;
                float xr = (float)xi_h[sb + j];
                float xz = (float)xi_h[sb + 16 + j];
                float xn = (float)xi_h[sb + 32 + j];
                float hr = 0.f, hz = 0.f, hn = c_hn0;
                #pragma unroll
                for (int k = 0; k < 16; k++){ hr += h0[k]*w0r[k]; hz += h0[k]*w0z[k]; hn += h0[k]*w0n[k]; }
                float r = sigm(xr + hr);
                float z = sigm(xz + hz);
                float n = tanh_f(xn + r*hn);
                hs0 = (1.f - z)*n + z*hs0;
                #pragma unroll
                for (int k = 0; k < 16; k++) h0[k] = __shfl(hs0, base + k);
                float ar = c_r1, az = c_z1, an = c_xn1, br = 0.f, bz = 0.f, bn = c_hn1;
                #pragma unroll
                for (int k = 0; k < 16; k++){
                    ar += h0[k]*wi1r[k]; az += h0[k]*wi1z[k]; an += h0[k]*wi1n[k];
                    br += h1[k]*wh1r[k]; bz += h1[k]*wh1z[k]; bn += h1[k]*wh1n[k];
                }
                float r1 = sigm(ar + br);
                float z1 = sigm(az + bz);
                float n1 = tanh_f(an + r1*bn);
                hs1 = (1.f - z1)*n1 + z1*hs1;
                gru_h[(b2*64 + s)*16 + j] = (_Float16)hs1;
                #pragma unroll
                for (int k = 0; k < 16; k++) h1[k] = __shfl(hs1, base + k);
            }
        }
        __syncthreads();
        // ---------------- phase 3: rel x7 + final MLP -> out ----------------
        {
            float g[16];
            #pragma unroll
            for (int i = 0; i < 16; i++) g[i] = (float)gru_h[(b1p*64 + tl)*16 + i];
            float wv[56];
            for (int s = 0; s < 7; s++){
                const float* ep = E_rel + (b1p*7+s)*8;   // includes rel_b0
                float p1[8], p2[8];
                #pragma unroll
                for (int i = 0; i < 8; i++){
                    float a = ep[i];
                    #pragma unroll
                    for (int k = 0; k < 16; k++) a += g[k]*rW0T[(s*8+i)*16+k];
                    p1[i] = elu_f(a);
                }
                #pragma unroll
                for (int i = 0; i < 8; i++){
                    float a = rbh[s*8+i];
                    #pragma unroll
                    for (int k = 0; k < 8; k++) a += p1[k]*rWhT[(s*8+i)*8+k];
                    p2[i] = elu_f(a);
                }
                float w = (float)csc_h[(b1p*7+s)*64 + tl];
                #pragma unroll
                for (int i = 0; i < 8; i++){
                    float a = rbo[s*8+i];
                    #pragma unroll
                    for (int k = 0; k < 8; k++) a += p2[k]*rWoT[(s*8+i)*8+k];
                    wv[s*8+i] = a*w;
                }
            }
            float f1[4], f2[4], o[4];
            #pragma unroll
            for (int cc = 0; cc < 4; cc++){
                float a = fb0[cc];
                #pragma unroll
                for (int k = 0; k < 16; k++) a += g[k]*fW0T[cc*72+k];
                #pragma unroll
                for (int k = 0; k < 56; k++) a += wv[k]*fW0T[cc*72+16+k];
                f1[cc] = elu_f(a);
            }
            #pragma unroll
            for (int cc = 0; cc < 4; cc++){
                float a = fbh[cc];
                #pragma unroll
                for (int k = 0; k < 4; k++) a += f1[k]*fWhT[cc*4+k];
                f2[cc] = elu_f(a);
            }
            #pragma unroll
            for (int cc = 0; cc < 4; cc++){
                float a = fbo[cc];
                #pragma unroll
                for (int k = 0; k < 4; k++) a += f2[k]*fWoT[cc*4+k];
                o[cc] = a;
            }
            size_t ofs = ((size_t)bb*TLEN + (t0 + tl))*4;   // out (B,T,4)
            if (F){
                float4 v; v.x = o[0]; v.y = o[1]; v.z = o[2]; v.w = o[3];
                *(float4*)((float*)out + ofs) = v;
            } else {
                u32 lo = (u32)f2bf(o[0]) | ((u32)f2bf(o[1]) << 16);
                u32 hi = (u32)f2bf(o[2]) | ((u32)f2bf(o[3]) << 16);
                *(uint2*)((u16*)out + ofs) = make_uint2(lo, hi);
            }
        }
        __syncthreads();   // protect chunk buffers before next phase 1
    }
}

extern "C" void kernel_launch(void* const* d_in, const int* in_sizes, int n_in,
                              void* d_out, int out_size, void* d_ws, size_t ws_size,
                              hipStream_t stream)
{
    (void)in_sizes; (void)n_in; (void)out_size; (void)d_ws; (void)ws_size;
    fused<<<dim3(256), dim3(256), 0, stream>>>(
        d_in[0],  d_in[1],
        d_in[2],  d_in[3],  d_in[4],  d_in[5],  d_in[6],  d_in[7],
        d_in[8],  d_in[9],  d_in[10], d_in[11], d_in[12], d_in[13],
        d_in[14], d_in[15],
        d_in[16], d_in[17], d_in[18], d_in[19], d_in[20], d_in[21],
        d_in[22], d_in[23], d_in[24], d_in[25],
        d_in[26], d_in[27], d_in[28], d_in[29],
        d_in[30], d_in[31], d_in[32], d_in[33], d_in[34], d_in[35],
        d_in[36], d_in[37], d_in[38], d_in[39], d_in[40], d_in[41],
        d_out);
}

// Round 7
// 1514.393 us; speedup vs baseline: 1.5701x; 1.5701x over previous
//
#include <hip/hip_runtime.h>
#include <hip/hip_bf16.h>
#include <hip/hip_fp16.h>
#include <stdint.h>

#define TLEN 512
#define TC 64
#define NCH (TLEN/TC)

typedef unsigned short u16;
typedef unsigned int u32;

__device__ __forceinline__ float b2f(u16 u){ union{u32 i; float f;} v; v.i = ((u32)u)<<16; return v.f; }
__device__ __forceinline__ u16 f2bf(float f){
    union{float f; u32 i;} v; v.f = f;
    u32 b = v.i; b += 0x7fffu + ((b>>16)&1u);   // RNE
    return (u16)(b>>16);
}
__device__ __forceinline__ float fexp2(float x){ return __builtin_amdgcn_exp2f(x); }
__device__ __forceinline__ float frcp(float x){ return __builtin_amdgcn_rcpf(x); }
#define LOG2E 1.4426950408889634f
__device__ __forceinline__ float elu_f(float x){ return x > 0.f ? x : fexp2(x*LOG2E) - 1.f; }
__device__ __forceinline__ float sigm(float x){ return frcp(1.f + fexp2(-LOG2E*x)); }
__device__ __forceinline__ float tanh_f(float x){ return 1.f - 2.f*frcp(1.f + fexp2((2.f*LOG2E)*x)); }

// dtype-adaptive load: F=true -> float32 buffer, else bf16 buffer
__device__ __forceinline__ float ldg(const void* p, int i, bool F){
    return F ? ((const float*)p)[i] : b2f(((const u16*)p)[i]);
}

__device__ void fill(float* dst, const void* src, int n, int tid, int nt, bool F){
    for (int i = tid; i < n; i += nt) dst[i] = ldg(src, i, F);
}
__device__ void fillS(float* dst, const void* src, int R, int C, int stride, int tid, int nt, bool F){
    for (int i = tid; i < R*C; i += nt){ int r = i / C, c = i % C; dst[i] = ldg(src, r*stride + c, F); }
}
// transposed: dst[i*K+k] = src[k*stride+i]
__device__ void fillT(float* dst, const void* src, int K, int I, int stride, int tid, int nt, bool F){
    for (int idx = tid; idx < K*I; idx += nt){ int i = idx / K, k = idx % K; dst[idx] = ldg(src, k*stride + i, F); }
}

__global__ __launch_bounds__(256,1) void fused(
    const void* envs, const void* states,
    const void* se_W0, const void* se_b0, const void* se_Wh, const void* se_bh, const void* se_Wo, const void* se_bo,
    const void* oe_W0, const void* oe_b0, const void* oe_Wh, const void* oe_bh, const void* oe_Wo, const void* oe_bo,
    const void* null_embed, const void* init_h,
    const void* att_W0, const void* att_b0, const void* att_Wh, const void* att_bh, const void* att_Wo, const void* att_bo,
    const void* gru0_Wi, const void* gru0_Wh, const void* gru0_bi, const void* gru0_bh,
    const void* gru1_Wi, const void* gru1_Wh, const void* gru1_bi, const void* gru1_bh,
    const void* rel_W0, const void* rel_b0, const void* rel_Wh, const void* rel_bh, const void* rel_Wo, const void* rel_bo,
    const void* fin_W0, const void* fin_b0, const void* fin_Wh, const void* fin_bh, const void* fin_Wo, const void* fin_bo,
    void* out)
{
    // persistent LDS
    __shared__ float sW0T[64], sb0[16], sWhT[768], sbh[48], sWoT[256], sbo[16];
    __shared__ float aW0T[256], aWhT[512], abh[32], aWo[16], abo_s[1];
    __shared__ float wi0se[768];
    __shared__ float rW0T[896], rWhT[448], rbh[56], rWoT[448], rbo[56];
    __shared__ float fW0T[288], fb0[4], fWhT[16], fbh[4], fWoT[16], fbo[4];
    __shared__ float E_att[448], E_rel[224], base_xi[192];
    __shared__ float uni[9088];         // union: phase-0 one-time buffers, then chunk buffers
    __shared__ int s_isf32;

    const int tid = threadIdx.x, nt = 256;
    const int blk = blockIdx.x;

    // ---------------- dtype detection (uniform, deterministic) ----------------
    if (tid == 0){
        const u16* p = (const u16*)se_W0;
        int ok = 1;
        #pragma unroll
        for (int k = 0; k < 8; k++){
            float v = fabsf(b2f(p[2*k]));
            ok &= (v > 1e-12f && v < 16.f) ? 1 : 0;
        }
        s_isf32 = ok ? 0 : 1;
    }
    __syncthreads();
    const bool F = (s_isf32 != 0);

    // ---------------- phase 0a: stage weights ----------------
    fillT(sW0T, se_W0, 4, 16, 16, tid, nt, F);
    fill (sb0, se_b0, 16, tid, nt, F);
    for (int l = 0; l < 3; l++) fillT(sWhT + l*256, (const u16*)se_Wh + (F?l*512:l*256), 16, 16, 16, tid, nt, F);
    fill (sbh, se_bh, 48, tid, nt, F);
    fillT(sWoT, se_Wo, 16, 16, 16, tid, nt, F);
    fill (sbo, se_bo, 16, tid, nt, F);
    fillT(aW0T, att_W0, 16, 16, 16, tid, nt, F);                 // se rows 0..15
    for (int l = 0; l < 2; l++) fillT(aWhT + l*256, (const u16*)att_Wh + (F?l*512:l*256), 16, 16, 16, tid, nt, F);
    fill (abh, att_bh, 32, tid, nt, F);
    fill (aWo, att_Wo, 16, tid, nt, F);
    fill (abo_s, att_bo, 1, tid, nt, F);
    fillS(wi0se, gru0_Wi, 48, 16, 128, tid, nt, F);              // se cols of Wi0
    for (int s = 0; s < 7; s++){
        fillT(rW0T + s*128, (const u16*)rel_W0 + (F?s*512:s*256), 16, 8, 8, tid, nt, F);   // gru rows 0..15
        fillT(rWhT + s*64, (const u16*)rel_Wh + (F?s*128:s*64), 8, 8, 8, tid, nt, F);
        fillT(rWoT + s*64, (const u16*)rel_Wo + (F?s*128:s*64), 8, 8, 8, tid, nt, F);
    }
    fill (rbh, rel_bh, 56, tid, nt, F);
    fill (rbo, rel_bo, 56, tid, nt, F);
    fillT(fW0T, fin_W0, 72, 4, 4, tid, nt, F);
    fill (fb0, fin_b0, 4, tid, nt, F);
    fillT(fWhT, fin_Wh, 4, 4, 4, tid, nt, F);
    fill (fbh, fin_bh, 4, tid, nt, F);
    fillT(fWoT, fin_Wo, 4, 4, 4, tid, nt, F);
    fill (fbo, fin_bo, 4, tid, nt, F);
    // one-time buffers inside uni
    float* oeW0T = uni;         // 144
    float* oeb0  = uni + 144;   // 48
    float* oeWhT = uni + 192;   // 2304
    float* oebh  = uni + 2496;  // 144
    float* oeWoT = uni + 2640;  // 768
    float* oebo  = uni + 3408;  // 48
    float* aW0To = uni + 3456;  // 256
    float* ab0   = uni + 3712;  // 16
    float* rW0To = uni + 3728;  // 896
    float* objE  = uni + 4624;  // 448
    for (int s = 0; s < 3; s++){
        fillT(oeW0T + s*48, (const u16*)oe_W0 + (F?s*96:s*48), 3, 16, 16, tid, nt, F);
        for (int l = 0; l < 3; l++)
            fillT(oeWhT + (s*3+l)*256, (const u16*)oe_Wh + (F?(s*3+l)*512:(s*3+l)*256), 16, 16, 16, tid, nt, F);
        fillT(oeWoT + s*256, (const u16*)oe_Wo + (F?s*512:s*256), 16, 16, 16, tid, nt, F);
    }
    fill(oeb0, oe_b0, 48, tid, nt, F);
    fill(oebh, oe_bh, 144, tid, nt, F);
    fill(oebo, oe_bo, 48, tid, nt, F);
    fillT(aW0To, (const u16*)att_W0 + (F?512:256), 16, 16, 16, tid, nt, F);  // obj rows 16..31
    fill (ab0, att_b0, 16, tid, nt, F);
    for (int s = 0; s < 7; s++)
        fillT(rW0To + s*128, (const u16*)rel_W0 + (F?(s*512+256):(s*256+128)), 16, 8, 8, tid, nt, F);  // obj rows
    __syncthreads();

    // ---------------- phase 0b: obj embeddings (28 units) ----------------
    if (tid < 28){
        int b1 = tid / 7, s = tid % 7;
        float o[16];
        if (s < 3){
            int b = blk*4 + b1;
            float x0 = ldg(envs, b*9+3*s, F), x1 = ldg(envs, b*9+3*s+1, F), x2 = ldg(envs, b*9+3*s+2, F);
            float h[16], h2[16];
            #pragma unroll
            for (int i = 0; i < 16; i++){
                float a = oeb0[s*16+i] + x0*oeW0T[s*48+i*3] + x1*oeW0T[s*48+i*3+1] + x2*oeW0T[s*48+i*3+2];
                h[i] = elu_f(a);
            }
            for (int l = 0; l < 3; l++){
                #pragma unroll
                for (int i = 0; i < 16; i++){
                    float a = oebh[(s*3+l)*16+i];
                    #pragma unroll
                    for (int k = 0; k < 16; k++) a += h[k]*oeWhT[((s*3+l)*16+i)*16+k];
                    h2[i] = elu_f(a);
                }
                #pragma unroll
                for (int i = 0; i < 16; i++) h[i] = h2[i];
            }
            #pragma unroll
            for (int i = 0; i < 16; i++){
                float a = oebo[s*16+i];
                #pragma unroll
                for (int k = 0; k < 16; k++) a += h[k]*oeWoT[(s*16+i)*16+k];
                o[i] = a;                       // linear output layer
            }
        } else {
            #pragma unroll
            for (int i = 0; i < 16; i++) o[i] = ldg(null_embed, (s-3)*16 + i, F);
        }
        #pragma unroll
        for (int i = 0; i < 16; i++) objE[(b1*7+s)*16 + i] = o[i];
    }
    __syncthreads();

    // ---------------- phase 0c: E_att, E_rel, base_xi ----------------
    for (int idx = tid; idx < 448; idx += nt){
        int r = idx % 112, i = r % 16;
        int os = (idx / 16) * 16;
        float a = ab0[i];
        #pragma unroll
        for (int k = 0; k < 16; k++) a += objE[os + k]*aW0To[i*16+k];
        E_att[idx] = a;
    }
    for (int idx = tid; idx < 224; idx += nt){
        int r = idx % 56, s = r / 8, i = r % 8;
        int b1 = idx / 56;
        float a = ldg(rel_b0, s*8+i, F);
        #pragma unroll
        for (int k = 0; k < 16; k++) a += objE[(b1*7+s)*16 + k]*rW0To[(s*8+i)*16+k];
        E_rel[idx] = a;
    }
    for (int idx = tid; idx < 192; idx += nt){
        int b1 = idx / 48, g = idx % 48;
        float a = ldg(gru0_bi, g, F) + (g < 32 ? ldg(gru0_bh, g, F) : 0.f);
        for (int s = 0; s < 7; s++){
            int wb = g*128 + 16 + s*16;
            #pragma unroll
            for (int k = 0; k < 16; k++) a += objE[(b1*7+s)*16 + k]*ldg(gru0_Wi, wb+k, F);
        }
        base_xi[idx] = a;
    }

    // ---------------- per-lane scan weights (one wave per b, lane = gate-row) ----
    // rows ordered r0..15, z16..31, n32..47 -> lane ln directly indexes row ln.
    const int wv = tid >> 6;            // wave index = local b
    const int ln = tid & 63;            // lane in wave
    float w0[16], wi1[16], wh1[16];
    float c0 = 0.f, c1a = 0.f, c1b = 0.f;
    if (ln < 48){
        #pragma unroll
        for (int k = 0; k < 16; k++){
            w0[k]  = ldg(gru0_Wh, ln*16+k, F);
            wi1[k] = ldg(gru1_Wi, ln*16+k, F);
            wh1[k] = ldg(gru1_Wh, ln*16+k, F);
        }
        if (ln >= 32) c0 = ldg(gru0_bh, ln, F);   // bh0_n[j], n-lanes only
        c1a = ldg(gru1_bi, ln, F);
        c1b = ldg(gru1_bh, ln, F);
    } else {
        #pragma unroll
        for (int k = 0; k < 16; k++){ w0[k] = 0.f; wi1[k] = 0.f; wh1[k] = 0.f; }
    }
    float h0[16], h1[16];
    #pragma unroll
    for (int k = 0; k < 16; k++){ h0[k] = ldg(init_h, k, F); h1[k] = ldg(init_h, 16+k, F); }
    __syncthreads();   // one-time uni region dead -> reuse as chunk buffers

    _Float16* xi_h  = (_Float16*)uni;            // 4b x 64t x 48
    _Float16* gru_h = (_Float16*)(uni + 6144);   // 4b x 64t x 16
    _Float16* csc_h = (_Float16*)(uni + 8192);   // 4b x 7s x 64t

    const int b1p = tid >> 6, tl = tid & 63;
    const int bb = blk*4 + b1p;

    for (int c = 0; c < NCH; c++){
        const int t0 = c*TC;
        // ---------------- phase 1: xi + colsc for chunk ----------------
        {
            const int t = t0 + tl;
            int sbase = ((int)bb*TLEN + t)*4;    // states (B,T,4)
            float x0 = ldg(states, sbase+0, F), x1 = ldg(states, sbase+1, F);
            float x2 = ldg(states, sbase+2, F), x3 = ldg(states, sbase+3, F);
            float h[16], h2[16];
            #pragma unroll
            for (int i = 0; i < 16; i++){
                float a = sb0[i] + x0*sW0T[i*4] + x1*sW0T[i*4+1] + x2*sW0T[i*4+2] + x3*sW0T[i*4+3];
                h[i] = fmaxf(a, 0.f);
            }
            for (int l = 0; l < 3; l++){
                #pragma unroll
                for (int i = 0; i < 16; i++){
                    float a = sbh[l*16+i];
                    #pragma unroll
                    for (int k = 0; k < 16; k++) a += h[k]*sWhT[(l*16+i)*16+k];
                    h2[i] = fmaxf(a, 0.f);
                }
                #pragma unroll
                for (int i = 0; i < 16; i++) h[i] = h2[i];
            }
            float se[16];
            #pragma unroll
            for (int i = 0; i < 16; i++){
                float a = sbo[i];
                #pragma unroll
                for (int k = 0; k < 16; k++) a += h[k]*sWoT[i*16+k];
                se[i] = a;
            }
            float satt[16];
            #pragma unroll
            for (int i = 0; i < 16; i++){
                float a = 0.f;
                #pragma unroll
                for (int k = 0; k < 16; k++) a += se[k]*aW0T[i*16+k];
                satt[i] = a;
            }
            float sc[7];
            for (int s = 0; s < 7; s++){
                const float* ep = E_att + (b1p*7+s)*16;   // includes att_b0
                float a1[16], a2[16];
                #pragma unroll
                for (int i = 0; i < 16; i++) a1[i] = elu_f(satt[i] + ep[i]);
                #pragma unroll
                for (int i = 0; i < 16; i++){
                    float a = abh[i];
                    #pragma unroll
                    for (int k = 0; k < 16; k++) a += a1[k]*aWhT[i*16+k];
                    a2[i] = elu_f(a);
                }
                #pragma unroll
                for (int i = 0; i < 16; i++){
                    float a = abh[16+i];
                    #pragma unroll
                    for (int k = 0; k < 16; k++) a += a2[k]*aWhT[256 + i*16+k];
                    a1[i] = elu_f(a);
                }
                float a = abo_s[0];
                #pragma unroll
                for (int k = 0; k < 16; k++) a += a1[k]*aWo[k];
                sc[s] = a;
            }
            float m = sc[0];
            #pragma unroll
            for (int s = 1; s < 7; s++) m = fmaxf(m, sc[s]);
            float e[7], sum = 0.f;
            #pragma unroll
            for (int s = 0; s < 7; s++){ e[s] = fexp2((sc[s]-m)*LOG2E); sum += e[s]; }
            float inv = frcp(sum);
            #pragma unroll
            for (int s = 0; s < 7; s++)
                csc_h[(b1p*7+s)*64 + tl] = (_Float16)(e[6-s]*inv);   // flip+softmax
            #pragma unroll
            for (int g = 0; g < 48; g++){
                float a = base_xi[b1p*48 + g];
                #pragma unroll
                for (int k = 0; k < 16; k++) a += se[k]*wi0se[g*16+k];
                xi_h[(b1p*64 + tl)*48 + g] = (_Float16)a;
            }
        }
        __syncthreads();
        // ------- phase 2: GRU scan — wave wv handles b=blk*4+wv, lanes 0..47 -------
        for (int s = 0; s < TC; s++){
            const int slot = wv*64 + s;
            float xv = (ln < 48) ? (float)xi_h[slot*48 + ln] : 0.f;
            // layer 0: acc = w0 . h0  (4 partials to shorten dep chain)
            float p0=0.f,p1=0.f,p2=0.f,p3=0.f;
            #pragma unroll
            for (int k = 0; k < 4; k++){
                p0 += h0[k]*w0[k];       p1 += h0[4+k]*w0[4+k];
                p2 += h0[8+k]*w0[8+k];   p3 += h0[12+k]*w0[12+k];
            }
            float accb = (p0+p1)+(p2+p3) + c0;   // c0=0 on r/z lanes; = bh0_n on n lanes
            float g = sigm(xv + accb);           // r gate on lanes 0..15, z on 16..31
            float rj = __shfl(g, ln & 15);
            float zj = __shfl(g, 16 + (ln & 15));
            float nn = tanh_f(xv + rj*accb);     // n on lanes 32..47 (xv has bi0_n)
            float hnew = (1.f - zj)*nn + zj*h0[ln & 15];
            #pragma unroll
            for (int k = 0; k < 16; k++) h0[k] = __shfl(hnew, 32+k);   // h0 <- y0
            // layer 1: a = bi1 + Wi1.h0new ; b = bh1 + Wh1.h1
            float q0=0.f,q1=0.f,q2=0.f,q3=0.f,u0=0.f,u1=0.f,u2=0.f,u3=0.f;
            #pragma unroll
            for (int k = 0; k < 4; k++){
                q0 += h0[k]*wi1[k];        u0 += h1[k]*wh1[k];
                q1 += h0[4+k]*wi1[4+k];    u1 += h1[4+k]*wh1[4+k];
                q2 += h0[8+k]*wi1[8+k];    u2 += h1[8+k]*wh1[8+k];
                q3 += h0[12+k]*wi1[12+k];  u3 += h1[12+k]*wh1[12+k];
            }
            float a = c1a + (q0+q1)+(q2+q3);
            float b = c1b + (u0+u1)+(u2+u3);
            float g1 = sigm(a + b);
            float r1 = __shfl(g1, ln & 15);
            float z1 = __shfl(g1, 16 + (ln & 15));
            float n1 = tanh_f(a + r1*b);
            float h1new = (1.f - z1)*n1 + z1*h1[ln & 15];
            if (ln >= 32 && ln < 48) gru_h[slot*16 + (ln - 32)] = (_Float16)h1new;
            #pragma unroll
            for (int k = 0; k < 16; k++) h1[k] = __shfl(h1new, 32+k);
        }
        __syncthreads();
        // ---------------- phase 3: rel x7 + final MLP -> out ----------------
        {
            float g[16];
            #pragma unroll
            for (int i = 0; i < 16; i++) g[i] = (float)gru_h[(b1p*64 + tl)*16 + i];
            float wvv[56];
            for (int s = 0; s < 7; s++){
                const float* ep = E_rel + (b1p*7+s)*8;   // includes rel_b0
                float p1a[8], p2a[8];
                #pragma unroll
                for (int i = 0; i < 8; i++){
                    float a = ep[i];
                    #pragma unroll
                    for (int k = 0; k < 16; k++) a += g[k]*rW0T[(s*8+i)*16+k];
                    p1a[i] = elu_f(a);
                }
                #pragma unroll
                for (int i = 0; i < 8; i++){
                    float a = rbh[s*8+i];
                    #pragma unroll
                    for (int k = 0; k < 8; k++) a += p1a[k]*rWhT[(s*8+i)*8+k];
                    p2a[i] = elu_f(a);
                }
                float w = (float)csc_h[(b1p*7+s)*64 + tl];
                #pragma unroll
                for (int i = 0; i < 8; i++){
                    float a = rbo[s*8+i];
                    #pragma unroll
                    for (int k = 0; k < 8; k++) a += p2a[k]*rWoT[(s*8+i)*8+k];
                    wvv[s*8+i] = a*w;
                }
            }
            float f1[4], f2[4], o[4];
            #pragma unroll
            for (int cc = 0; cc < 4; cc++){
                float a = fb0[cc];
                #pragma unroll
                for (int k = 0; k < 16; k++) a += g[k]*fW0T[cc*72+k];
                #pragma unroll
                for (int k = 0; k < 56; k++) a += wvv[k]*fW0T[cc*72+16+k];
                f1[cc] = elu_f(a);
            }
            #pragma unroll
            for (int cc = 0; cc < 4; cc++){
                float a = fbh[cc];
                #pragma unroll
                for (int k = 0; k < 4; k++) a += f1[k]*fWhT[cc*4+k];
                f2[cc] = elu_f(a);
            }
            #pragma unroll
            for (int cc = 0; cc < 4; cc++){
                float a = fbo[cc];
                #pragma unroll
                for (int k = 0; k < 4; k++) a += f2[k]*fWoT[cc*4+k];
                o[cc] = a;
            }
            size_t ofs = ((size_t)bb*TLEN + (t0 + tl))*4;   // out (B,T,4)
            if (F){
                float4 v; v.x = o[0]; v.y = o[1]; v.z = o[2]; v.w = o[3];
                *(float4*)((float*)out + ofs) = v;
            } else {
                u32 lo = (u32)f2bf(o[0]) | ((u32)f2bf(o[1]) << 16);
                u32 hi = (u32)f2bf(o[2]) | ((u32)f2bf(o[3]) << 16);
                *(uint2*)((u16*)out + ofs) = make_uint2(lo, hi);
            }
        }
        __syncthreads();   // protect chunk buffers before next phase 1
    }
}

extern "C" void kernel_launch(void* const* d_in, const int* in_sizes, int n_in,
                              void* d_out, int out_size, void* d_ws, size_t ws_size,
                              hipStream_t stream)
{
    (void)in_sizes; (void)n_in; (void)out_size; (void)d_ws; (void)ws_size;
    fused<<<dim3(256), dim3(256), 0, stream>>>(
        d_in[0],  d_in[1],
        d_in[2],  d_in[3],  d_in[4],  d_in[5],  d_in[6],  d_in[7],
        d_in[8],  d_in[9],  d_in[10], d_in[11], d_in[12], d_in[13],
        d_in[14], d_in[15],
        d_in[16], d_in[17], d_in[18], d_in[19], d_in[20], d_in[21],
        d_in[22], d_in[23], d_in[24], d_in[25],
        d_in[26], d_in[27], d_in[28], d_in[29],
        d_in[30], d_in[31], d_in[32], d_in[33], d_in[34], d_in[35],
        d_in[36], d_in[37], d_in[38], d_in[39], d_in[40], d_in[41],
        d_out);
}

// Round 8
// 1509.726 us; speedup vs baseline: 1.5750x; 1.0031x over previous
//
#include <hip/hip_runtime.h>
#include <hip/hip_bf16.h>
#include <hip/hip_fp16.h>
#include <stdint.h>

#define TLEN 512
#define TC 64
#define NCH (TLEN/TC)

typedef unsigned short u16;
typedef unsigned int u32;

__device__ __forceinline__ float b2f(u16 u){ union{u32 i; float f;} v; v.i = ((u32)u)<<16; return v.f; }
__device__ __forceinline__ u16 f2bf(float f){
    union{float f; u32 i;} v; v.f = f;
    u32 b = v.i; b += 0x7fffu + ((b>>16)&1u);   // RNE
    return (u16)(b>>16);
}
__device__ __forceinline__ float fexp2(float x){ return __builtin_amdgcn_exp2f(x); }
__device__ __forceinline__ float frcp(float x){ return __builtin_amdgcn_rcpf(x); }
#define LOG2E 1.4426950408889634f
__device__ __forceinline__ float elu_f(float x){ return x > 0.f ? x : fexp2(x*LOG2E) - 1.f; }
__device__ __forceinline__ float sigm(float x){ return frcp(1.f + fexp2(-LOG2E*x)); }
__device__ __forceinline__ float tanh_f(float x){ return 1.f - 2.f*frcp(1.f + fexp2((2.f*LOG2E)*x)); }

// dtype-adaptive load: F=true -> float32 buffer, else bf16 buffer
__device__ __forceinline__ float ldg(const void* p, int i, bool F){
    return F ? ((const float*)p)[i] : b2f(((const u16*)p)[i]);
}

__device__ void fill(float* dst, const void* src, int n, int tid, int nt, bool F){
    for (int i = tid; i < n; i += nt) dst[i] = ldg(src, i, F);
}
__device__ void fillS(float* dst, const void* src, int R, int C, int stride, int tid, int nt, bool F){
    for (int i = tid; i < R*C; i += nt){ int r = i / C, c = i % C; dst[i] = ldg(src, r*stride + c, F); }
}
// transposed: dst[i*K+k] = src[k*stride+i]
__device__ void fillT(float* dst, const void* src, int K, int I, int stride, int tid, int nt, bool F){
    for (int idx = tid; idx < K*I; idx += nt){ int i = idx / K, k = idx % K; dst[idx] = ldg(src, k*stride + i, F); }
}

__global__ __launch_bounds__(256,1) void fused(
    const void* envs, const void* states,
    const void* se_W0, const void* se_b0, const void* se_Wh, const void* se_bh, const void* se_Wo, const void* se_bo,
    const void* oe_W0, const void* oe_b0, const void* oe_Wh, const void* oe_bh, const void* oe_Wo, const void* oe_bo,
    const void* null_embed, const void* init_h,
    const void* att_W0, const void* att_b0, const void* att_Wh, const void* att_bh, const void* att_Wo, const void* att_bo,
    const void* gru0_Wi, const void* gru0_Wh, const void* gru0_bi, const void* gru0_bh,
    const void* gru1_Wi, const void* gru1_Wh, const void* gru1_bi, const void* gru1_bh,
    const void* rel_W0, const void* rel_b0, const void* rel_Wh, const void* rel_bh, const void* rel_Wo, const void* rel_bo,
    const void* fin_W0, const void* fin_b0, const void* fin_Wh, const void* fin_bh, const void* fin_Wo, const void* fin_bo,
    void* out)
{
    // persistent LDS
    __shared__ float sW0T[64], sb0[16], sWhT[768], sbh[48], sWoT[256], sbo[16];
    __shared__ float aW0T[256], aWhT[512], abh[32], aWo[16], abo_s[1];
    __shared__ float wi0se[768];
    __shared__ float rW0T[896], rWhT[448], rbh[56], rWoT[448], rbo[56];
    __shared__ float fW0T[288], fb0[4], fWhT[16], fbh[4], fWoT[16], fbo[4];
    __shared__ float E_att[448], E_rel[224], base_xi[192];
    __shared__ float uni[9088];         // union: phase-0 one-time buffers, then chunk buffers
    __shared__ int s_isf32;

    const int tid = threadIdx.x, nt = 256;
    const int blk = blockIdx.x;

    // ---------------- dtype detection (uniform, deterministic) ----------------
    if (tid == 0){
        const u16* p = (const u16*)se_W0;
        int ok = 1;
        #pragma unroll
        for (int k = 0; k < 8; k++){
            float v = fabsf(b2f(p[2*k]));
            ok &= (v > 1e-12f && v < 16.f) ? 1 : 0;
        }
        s_isf32 = ok ? 0 : 1;
    }
    __syncthreads();
    const bool F = (s_isf32 != 0);

    // ---------------- phase 0a: stage weights ----------------
    fillT(sW0T, se_W0, 4, 16, 16, tid, nt, F);
    fill (sb0, se_b0, 16, tid, nt, F);
    for (int l = 0; l < 3; l++) fillT(sWhT + l*256, (const u16*)se_Wh + (F?l*512:l*256), 16, 16, 16, tid, nt, F);
    fill (sbh, se_bh, 48, tid, nt, F);
    fillT(sWoT, se_Wo, 16, 16, 16, tid, nt, F);
    fill (sbo, se_bo, 16, tid, nt, F);
    fillT(aW0T, att_W0, 16, 16, 16, tid, nt, F);                 // se rows 0..15
    for (int l = 0; l < 2; l++) fillT(aWhT + l*256, (const u16*)att_Wh + (F?l*512:l*256), 16, 16, 16, tid, nt, F);
    fill (abh, att_bh, 32, tid, nt, F);
    fill (aWo, att_Wo, 16, tid, nt, F);
    fill (abo_s, att_bo, 1, tid, nt, F);
    fillS(wi0se, gru0_Wi, 48, 16, 128, tid, nt, F);              // se cols of Wi0
    for (int s = 0; s < 7; s++){
        fillT(rW0T + s*128, (const u16*)rel_W0 + (F?s*512:s*256), 16, 8, 8, tid, nt, F);   // gru rows 0..15
        fillT(rWhT + s*64, (const u16*)rel_Wh + (F?s*128:s*64), 8, 8, 8, tid, nt, F);
        fillT(rWoT + s*64, (const u16*)rel_Wo + (F?s*128:s*64), 8, 8, 8, tid, nt, F);
    }
    fill (rbh, rel_bh, 56, tid, nt, F);
    fill (rbo, rel_bo, 56, tid, nt, F);
    fillT(fW0T, fin_W0, 72, 4, 4, tid, nt, F);
    fill (fb0, fin_b0, 4, tid, nt, F);
    fillT(fWhT, fin_Wh, 4, 4, 4, tid, nt, F);
    fill (fbh, fin_bh, 4, tid, nt, F);
    fillT(fWoT, fin_Wo, 4, 4, 4, tid, nt, F);
    fill (fbo, fin_bo, 4, tid, nt, F);
    // one-time buffers inside uni
    float* oeW0T = uni;         // 144
    float* oeb0  = uni + 144;   // 48
    float* oeWhT = uni + 192;   // 2304
    float* oebh  = uni + 2496;  // 144
    float* oeWoT = uni + 2640;  // 768
    float* oebo  = uni + 3408;  // 48
    float* aW0To = uni + 3456;  // 256
    float* ab0   = uni + 3712;  // 16
    float* rW0To = uni + 3728;  // 896
    float* objE  = uni + 4624;  // 448
    for (int s = 0; s < 3; s++){
        fillT(oeW0T + s*48, (const u16*)oe_W0 + (F?s*96:s*48), 3, 16, 16, tid, nt, F);
        for (int l = 0; l < 3; l++)
            fillT(oeWhT + (s*3+l)*256, (const u16*)oe_Wh + (F?(s*3+l)*512:(s*3+l)*256), 16, 16, 16, tid, nt, F);
        fillT(oeWoT + s*256, (const u16*)oe_Wo + (F?s*512:s*256), 16, 16, 16, tid, nt, F);
    }
    fill(oeb0, oe_b0, 48, tid, nt, F);
    fill(oebh, oe_bh, 144, tid, nt, F);
    fill(oebo, oe_bo, 48, tid, nt, F);
    fillT(aW0To, (const u16*)att_W0 + (F?512:256), 16, 16, 16, tid, nt, F);  // obj rows 16..31
    fill (ab0, att_b0, 16, tid, nt, F);
    for (int s = 0; s < 7; s++)
        fillT(rW0To + s*128, (const u16*)rel_W0 + (F?(s*512+256):(s*256+128)), 16, 8, 8, tid, nt, F);  // obj rows
    __syncthreads();

    // ---------------- phase 0b: obj embeddings (28 units) ----------------
    if (tid < 28){
        int b1 = tid / 7, s = tid % 7;
        float o[16];
        if (s < 3){
            int b = blk*4 + b1;
            float x0 = ldg(envs, b*9+3*s, F), x1 = ldg(envs, b*9+3*s+1, F), x2 = ldg(envs, b*9+3*s+2, F);
            float h[16], h2[16];
            #pragma unroll
            for (int i = 0; i < 16; i++){
                float a = oeb0[s*16+i] + x0*oeW0T[s*48+i*3] + x1*oeW0T[s*48+i*3+1] + x2*oeW0T[s*48+i*3+2];
                h[i] = elu_f(a);
            }
            for (int l = 0; l < 3; l++){
                #pragma unroll
                for (int i = 0; i < 16; i++){
                    float a = oebh[(s*3+l)*16+i];
                    #pragma unroll
                    for (int k = 0; k < 16; k++) a += h[k]*oeWhT[((s*3+l)*16+i)*16+k];
                    h2[i] = elu_f(a);
                }
                #pragma unroll
                for (int i = 0; i < 16; i++) h[i] = h2[i];
            }
            #pragma unroll
            for (int i = 0; i < 16; i++){
                float a = oebo[s*16+i];
                #pragma unroll
                for (int k = 0; k < 16; k++) a += h[k]*oeWoT[(s*16+i)*16+k];
                o[i] = a;                       // linear output layer
            }
        } else {
            #pragma unroll
            for (int i = 0; i < 16; i++) o[i] = ldg(null_embed, (s-3)*16 + i, F);
        }
        #pragma unroll
        for (int i = 0; i < 16; i++) objE[(b1*7+s)*16 + i] = o[i];
    }
    __syncthreads();

    // ---------------- phase 0c: E_att, E_rel, base_xi ----------------
    for (int idx = tid; idx < 448; idx += nt){
        int r = idx % 112, i = r % 16;
        int os = (idx / 16) * 16;
        float a = ab0[i];
        #pragma unroll
        for (int k = 0; k < 16; k++) a += objE[os + k]*aW0To[i*16+k];
        E_att[idx] = a;
    }
    for (int idx = tid; idx < 224; idx += nt){
        int r = idx % 56, s = r / 8, i = r % 8;
        int b1 = idx / 56;
        float a = ldg(rel_b0, s*8+i, F);
        #pragma unroll
        for (int k = 0; k < 16; k++) a += objE[(b1*7+s)*16 + k]*rW0To[(s*8+i)*16+k];
        E_rel[idx] = a;
    }
    for (int idx = tid; idx < 192; idx += nt){
        int b1 = idx / 48, g = idx % 48;
        float a = ldg(gru0_bi, g, F) + (g < 32 ? ldg(gru0_bh, g, F) : 0.f);
        for (int s = 0; s < 7; s++){
            int wb = g*128 + 16 + s*16;
            #pragma unroll
            for (int k = 0; k < 16; k++) a += objE[(b1*7+s)*16 + k]*ldg(gru0_Wi, wb+k, F);
        }
        base_xi[idx] = a;
    }

    // ---------------- per-lane scan weights (one wave per b, lane = gate-row) ----
    // rows ordered r0..15, z16..31, n32..47 -> lane ln directly indexes row ln.
    const int wv = tid >> 6;            // wave index = local b
    const int ln = tid & 63;            // lane in wave
    const int lj = ln & 15;             // lane's h-index
    float w0[16], wi1[16], wh1[16];
    float c0 = 0.f, c1a = 0.f, c1b = 0.f;
    if (ln < 48){
        #pragma unroll
        for (int k = 0; k < 16; k++){
            w0[k]  = ldg(gru0_Wh, ln*16+k, F);
            wi1[k] = ldg(gru1_Wi, ln*16+k, F);
            wh1[k] = ldg(gru1_Wh, ln*16+k, F);
        }
        if (ln >= 32) c0 = ldg(gru0_bh, ln, F);   // bh0_n[j], n-lanes only
        c1a = ldg(gru1_bi, ln, F);
        c1b = ldg(gru1_bh, ln, F);
    } else {
        #pragma unroll
        for (int k = 0; k < 16; k++){ w0[k] = 0.f; wi1[k] = 0.f; wh1[k] = 0.f; }
    }
    float h0[16], h1[16];
    #pragma unroll
    for (int k = 0; k < 16; k++){ h0[k] = ldg(init_h, k, F); h1[k] = ldg(init_h, 16+k, F); }
    float hp0 = ldg(init_h, lj, F);        // this lane's h_prev[j], scalar (no dyn index)
    float hp1 = ldg(init_h, 16 + lj, F);
    __syncthreads();   // one-time uni region dead -> reuse as chunk buffers

    _Float16* xi_h  = (_Float16*)uni;            // 4b x 64t x 48
    _Float16* gru_h = (_Float16*)(uni + 6144);   // 4b x 64t x 16
    _Float16* csc_h = (_Float16*)(uni + 8192);   // 4b x 7s x 64t

    const int b1p = tid >> 6, tl = tid & 63;
    const int bb = blk*4 + b1p;

    for (int c = 0; c < NCH; c++){
        const int t0 = c*TC;
        // ---------------- phase 1: xi + colsc for chunk ----------------
        {
            const int t = t0 + tl;
            int sbase = ((int)bb*TLEN + t)*4;    // states (B,T,4)
            float x0 = ldg(states, sbase+0, F), x1 = ldg(states, sbase+1, F);
            float x2 = ldg(states, sbase+2, F), x3 = ldg(states, sbase+3, F);
            float h[16], h2[16];
            #pragma unroll
            for (int i = 0; i < 16; i++){
                float a = sb0[i] + x0*sW0T[i*4] + x1*sW0T[i*4+1] + x2*sW0T[i*4+2] + x3*sW0T[i*4+3];
                h[i] = fmaxf(a, 0.f);
            }
            for (int l = 0; l < 3; l++){
                #pragma unroll
                for (int i = 0; i < 16; i++){
                    float a = sbh[l*16+i];
                    #pragma unroll
                    for (int k = 0; k < 16; k++) a += h[k]*sWhT[(l*16+i)*16+k];
                    h2[i] = fmaxf(a, 0.f);
                }
                #pragma unroll
                for (int i = 0; i < 16; i++) h[i] = h2[i];
            }
            float se[16];
            #pragma unroll
            for (int i = 0; i < 16; i++){
                float a = sbo[i];
                #pragma unroll
                for (int k = 0; k < 16; k++) a += h[k]*sWoT[i*16+k];
                se[i] = a;
            }
            float satt[16];
            #pragma unroll
            for (int i = 0; i < 16; i++){
                float a = 0.f;
                #pragma unroll
                for (int k = 0; k < 16; k++) a += se[k]*aW0T[i*16+k];
                satt[i] = a;
            }
            float sc[7];
            for (int s = 0; s < 7; s++){
                const float* ep = E_att + (b1p*7+s)*16;   // includes att_b0
                float a1[16], a2[16];
                #pragma unroll
                for (int i = 0; i < 16; i++) a1[i] = elu_f(satt[i] + ep[i]);
                #pragma unroll
                for (int i = 0; i < 16; i++){
                    float a = abh[i];
                    #pragma unroll
                    for (int k = 0; k < 16; k++) a += a1[k]*aWhT[i*16+k];
                    a2[i] = elu_f(a);
                }
                #pragma unroll
                for (int i = 0; i < 16; i++){
                    float a = abh[16+i];
                    #pragma unroll
                    for (int k = 0; k < 16; k++) a += a2[k]*aWhT[256 + i*16+k];
                    a1[i] = elu_f(a);
                }
                float a = abo_s[0];
                #pragma unroll
                for (int k = 0; k < 16; k++) a += a1[k]*aWo[k];
                sc[s] = a;
            }
            float m = sc[0];
            #pragma unroll
            for (int s = 1; s < 7; s++) m = fmaxf(m, sc[s]);
            float e[7], sum = 0.f;
            #pragma unroll
            for (int s = 0; s < 7; s++){ e[s] = fexp2((sc[s]-m)*LOG2E); sum += e[s]; }
            float inv = frcp(sum);
            #pragma unroll
            for (int s = 0; s < 7; s++)
                csc_h[(b1p*7+s)*64 + tl] = (_Float16)(e[6-s]*inv);   // flip+softmax
            #pragma unroll
            for (int g = 0; g < 48; g++){
                float a = base_xi[b1p*48 + g];
                #pragma unroll
                for (int k = 0; k < 16; k++) a += se[k]*wi0se[g*16+k];
                xi_h[(b1p*64 + tl)*48 + g] = (_Float16)a;
            }
        }
        __syncthreads();
        // ------- phase 2: GRU scan — wave wv handles b=blk*4+wv, lanes 0..47 -------
        for (int s = 0; s < TC; s++){
            const int slot = wv*64 + s;
            float xv = (ln < 48) ? (float)xi_h[slot*48 + ln] : 0.f;
            // layer 0: acc = w0 . h0  (4 partials to shorten dep chain)
            float p0=0.f,p1=0.f,p2=0.f,p3=0.f;
            #pragma unroll
            for (int k = 0; k < 4; k++){
                p0 += h0[k]*w0[k];       p1 += h0[4+k]*w0[4+k];
                p2 += h0[8+k]*w0[8+k];   p3 += h0[12+k]*w0[12+k];
            }
            float accb = (p0+p1)+(p2+p3) + c0;   // c0=0 on r/z lanes; = bh0_n on n lanes
            float g = sigm(xv + accb);           // r gate on lanes 0..15, z on 16..31
            float rj = __shfl(g, lj);
            float zj = __shfl(g, 16 + lj);
            float nn = tanh_f(xv + rj*accb);     // n on lanes 32..47 (xv has bi0_n)
            float hnew = (1.f - zj)*nn + zj*hp0; // meaningful on n-lanes
            hp0 = __shfl(hnew, 32 + lj);         // scalar h_prev[j] for next step
            #pragma unroll
            for (int k = 0; k < 16; k++) h0[k] = __shfl(hnew, 32+k);   // h0 <- y0
            // layer 1: a = bi1 + Wi1.h0new ; b = bh1 + Wh1.h1
            float q0=0.f,q1=0.f,q2=0.f,q3=0.f,u0=0.f,u1=0.f,u2=0.f,u3=0.f;
            #pragma unroll
            for (int k = 0; k < 4; k++){
                q0 += h0[k]*wi1[k];        u0 += h1[k]*wh1[k];
                q1 += h0[4+k]*wi1[4+k];    u1 += h1[4+k]*wh1[4+k];
                q2 += h0[8+k]*wi1[8+k];    u2 += h1[8+k]*wh1[8+k];
                q3 += h0[12+k]*wi1[12+k];  u3 += h1[12+k]*wh1[12+k];
            }
            float a = c1a + (q0+q1)+(q2+q3);
            float b = c1b + (u0+u1)+(u2+u3);
            float g1 = sigm(a + b);
            float r1 = __shfl(g1, lj);
            float z1 = __shfl(g1, 16 + lj);
            float n1 = tanh_f(a + r1*b);
            float h1new = (1.f - z1)*n1 + z1*hp1;
            hp1 = __shfl(h1new, 32 + lj);
            if (ln >= 32 && ln < 48) gru_h[slot*16 + (ln - 32)] = (_Float16)h1new;
            #pragma unroll
            for (int k = 0; k < 16; k++) h1[k] = __shfl(h1new, 32+k);
        }
        __syncthreads();
        // ---------------- phase 3: rel x7 + final MLP -> out ----------------
        {
            float g[16];
            #pragma unroll
            for (int i = 0; i < 16; i++) g[i] = (float)gru_h[(b1p*64 + tl)*16 + i];
            float wvv[56];
            for (int s = 0; s < 7; s++){
                const float* ep = E_rel + (b1p*7+s)*8;   // includes rel_b0
                float p1a[8], p2a[8];
                #pragma unroll
                for (int i = 0; i < 8; i++){
                    float a = ep[i];
                    #pragma unroll
                    for (int k = 0; k < 16; k++) a += g[k]*rW0T[(s*8+i)*16+k];
                    p1a[i] = elu_f(a);
                }
                #pragma unroll
                for (int i = 0; i < 8; i++){
                    float a = rbh[s*8+i];
                    #pragma unroll
                    for (int k = 0; k < 8; k++) a += p1a[k]*rWhT[(s*8+i)*8+k];
                    p2a[i] = elu_f(a);
                }
                float w = (float)csc_h[(b1p*7+s)*64 + tl];
                #pragma unroll
                for (int i = 0; i < 8; i++){
                    float a = rbo[s*8+i];
                    #pragma unroll
                    for (int k = 0; k < 8; k++) a += p2a[k]*rWoT[(s*8+i)*8+k];
                    wvv[s*8+i] = a*w;
                }
            }
            float f1[4], f2[4], o[4];
            #pragma unroll
            for (int cc = 0; cc < 4; cc++){
                float a = fb0[cc];
                #pragma unroll
                for (int k = 0; k < 16; k++) a += g[k]*fW0T[cc*72+k];
                #pragma unroll
                for (int k = 0; k < 56; k++) a += wvv[k]*fW0T[cc*72+16+k];
                f1[cc] = elu_f(a);
            }
            #pragma unroll
            for (int cc = 0; cc < 4; cc++){
                float a = fbh[cc];
                #pragma unroll
                for (int k = 0; k < 4; k++) a += f1[k]*fWhT[cc*4+k];
                f2[cc] = elu_f(a);
            }
            #pragma unroll
            for (int cc = 0; cc < 4; cc++){
                float a = fbo[cc];
                #pragma unroll
                for (int k = 0; k < 4; k++) a += f2[k]*fWoT[cc*4+k];
                o[cc] = a;
            }
            size_t ofs = ((size_t)bb*TLEN + (t0 + tl))*4;   // out (B,T,4)
            if (F){
                float4 v; v.x = o[0]; v.y = o[1]; v.z = o[2]; v.w = o[3];
                *(float4*)((float*)out + ofs) = v;
            } else {
                u32 lo = (u32)f2bf(o[0]) | ((u32)f2bf(o[1]) << 16);
                u32 hi = (u32)f2bf(o[2]) | ((u32)f2bf(o[3]) << 16);
                *(uint2*)((u16*)out + ofs) = make_uint2(lo, hi);
            }
        }
        __syncthreads();   // protect chunk buffers before next phase 1
    }
}

extern "C" void kernel_launch(void* const* d_in, const int* in_sizes, int n_in,
                              void* d_out, int out_size, void* d_ws, size_t ws_size,
                              hipStream_t stream)
{
    (void)in_sizes; (void)n_in; (void)out_size; (void)d_ws; (void)ws_size;
    fused<<<dim3(256), dim3(256), 0, stream>>>(
        d_in[0],  d_in[1],
        d_in[2],  d_in[3],  d_in[4],  d_in[5],  d_in[6],  d_in[7],
        d_in[8],  d_in[9],  d_in[10], d_in[11], d_in[12], d_in[13],
        d_in[14], d_in[15],
        d_in[16], d_in[17], d_in[18], d_in[19], d_in[20], d_in[21],
        d_in[22], d_in[23], d_in[24], d_in[25],
        d_in[26], d_in[27], d_in[28], d_in[29],
        d_in[30], d_in[31], d_in[32], d_in[33], d_in[34], d_in[35],
        d_in[36], d_in[37], d_in[38], d_in[39], d_in[40], d_in[41],
        d_out);
}

// Round 9
// 1103.465 us; speedup vs baseline: 2.1549x; 1.3682x over previous
//
#include <hip/hip_runtime.h>
#include <hip/hip_bf16.h>
#include <hip/hip_fp16.h>
#include <stdint.h>

#define TLEN 512
#define TC 64
#define NCH (TLEN/TC)

typedef unsigned short u16;
typedef unsigned int u32;

__device__ __forceinline__ float b2f(u16 u){ union{u32 i; float f;} v; v.i = ((u32)u)<<16; return v.f; }
__device__ __forceinline__ u16 f2bf(float f){
    union{float f; u32 i;} v; v.f = f;
    u32 b = v.i; b += 0x7fffu + ((b>>16)&1u);   // RNE
    return (u16)(b>>16);
}
__device__ __forceinline__ float fexp2(float x){ return __builtin_amdgcn_exp2f(x); }
__device__ __forceinline__ float frcp(float x){ return __builtin_amdgcn_rcpf(x); }
#define LOG2E 1.4426950408889634f
__device__ __forceinline__ float elu_f(float x){ return x > 0.f ? x : fexp2(x*LOG2E) - 1.f; }
__device__ __forceinline__ float sigm(float x){ return frcp(1.f + fexp2(-LOG2E*x)); }
__device__ __forceinline__ float tanh_f(float x){ return 1.f - 2.f*frcp(1.f + fexp2((2.f*LOG2E)*x)); }

// dtype-adaptive load: F=true -> float32 buffer, else bf16 buffer
__device__ __forceinline__ float ldg(const void* p, int i, bool F){
    return F ? ((const float*)p)[i] : b2f(((const u16*)p)[i]);
}

__device__ void fill(float* dst, const void* src, int n, int tid, int nt, bool F){
    for (int i = tid; i < n; i += nt) dst[i] = ldg(src, i, F);
}
__device__ void fillS(float* dst, const void* src, int R, int C, int stride, int tid, int nt, bool F){
    for (int i = tid; i < R*C; i += nt){ int r = i / C, c = i % C; dst[i] = ldg(src, r*stride + c, F); }
}
// transposed: dst[i*K+k] = src[k*stride+i]
__device__ void fillT(float* dst, const void* src, int K, int I, int stride, int tid, int nt, bool F){
    for (int idx = tid; idx < K*I; idx += nt){ int i = idx / K, k = idx % K; dst[idx] = ldg(src, k*stride + i, F); }
}

__global__ __launch_bounds__(256,1) void fused(
    const void* envs, const void* states,
    const void* se_W0, const void* se_b0, const void* se_Wh, const void* se_bh, const void* se_Wo, const void* se_bo,
    const void* oe_W0, const void* oe_b0, const void* oe_Wh, const void* oe_bh, const void* oe_Wo, const void* oe_bo,
    const void* null_embed, const void* init_h,
    const void* att_W0, const void* att_b0, const void* att_Wh, const void* att_bh, const void* att_Wo, const void* att_bo,
    const void* gru0_Wi, const void* gru0_Wh, const void* gru0_bi, const void* gru0_bh,
    const void* gru1_Wi, const void* gru1_Wh, const void* gru1_bi, const void* gru1_bh,
    const void* rel_W0, const void* rel_b0, const void* rel_Wh, const void* rel_bh, const void* rel_Wo, const void* rel_bo,
    const void* fin_W0, const void* fin_b0, const void* fin_Wh, const void* fin_bh, const void* fin_Wo, const void* fin_bo,
    void* out)
{
    // persistent LDS
    __shared__ float sW0T[64], sb0[16], sWhT[768], sbh[48], sWoT[256], sbo[16];
    __shared__ float aW0T[256], aWhT[512], abh[32], aWo[16], abo_s[1];
    __shared__ float wi0se[768];
    __shared__ float rW0T[896], rWhT[448], rbh[56], rWoT[448], rbo[56];
    __shared__ float fW0T[288], fb0[4], fWhT[16], fbh[4], fWoT[16], fbo[4];
    __shared__ float E_att[448], E_rel[224], base_xi[192];
    __shared__ float uni[9088];         // union: phase-0 one-time buffers, then chunk buffers
    __shared__ int s_isf32;

    const int tid = threadIdx.x, nt = 256;
    const int blk = blockIdx.x;

    // ---------------- dtype detection (uniform, deterministic) ----------------
    if (tid == 0){
        const u16* p = (const u16*)se_W0;
        int ok = 1;
        #pragma unroll
        for (int k = 0; k < 8; k++){
            float v = fabsf(b2f(p[2*k]));
            ok &= (v > 1e-12f && v < 16.f) ? 1 : 0;
        }
        s_isf32 = ok ? 0 : 1;
    }
    __syncthreads();
    const bool F = (s_isf32 != 0);

    // ---------------- phase 0a: stage weights ----------------
    fillT(sW0T, se_W0, 4, 16, 16, tid, nt, F);
    fill (sb0, se_b0, 16, tid, nt, F);
    for (int l = 0; l < 3; l++) fillT(sWhT + l*256, (const u16*)se_Wh + (F?l*512:l*256), 16, 16, 16, tid, nt, F);
    fill (sbh, se_bh, 48, tid, nt, F);
    fillT(sWoT, se_Wo, 16, 16, 16, tid, nt, F);
    fill (sbo, se_bo, 16, tid, nt, F);
    fillT(aW0T, att_W0, 16, 16, 16, tid, nt, F);                 // se rows 0..15
    for (int l = 0; l < 2; l++) fillT(aWhT + l*256, (const u16*)att_Wh + (F?l*512:l*256), 16, 16, 16, tid, nt, F);
    fill (abh, att_bh, 32, tid, nt, F);
    fill (aWo, att_Wo, 16, tid, nt, F);
    fill (abo_s, att_bo, 1, tid, nt, F);
    fillS(wi0se, gru0_Wi, 48, 16, 128, tid, nt, F);              // se cols of Wi0
    for (int s = 0; s < 7; s++){
        fillT(rW0T + s*128, (const u16*)rel_W0 + (F?s*512:s*256), 16, 8, 8, tid, nt, F);   // gru rows 0..15
        fillT(rWhT + s*64, (const u16*)rel_Wh + (F?s*128:s*64), 8, 8, 8, tid, nt, F);
        fillT(rWoT + s*64, (const u16*)rel_Wo + (F?s*128:s*64), 8, 8, 8, tid, nt, F);
    }
    fill (rbh, rel_bh, 56, tid, nt, F);
    fill (rbo, rel_bo, 56, tid, nt, F);
    fillT(fW0T, fin_W0, 72, 4, 4, tid, nt, F);
    fill (fb0, fin_b0, 4, tid, nt, F);
    fillT(fWhT, fin_Wh, 4, 4, 4, tid, nt, F);
    fill (fbh, fin_bh, 4, tid, nt, F);
    fillT(fWoT, fin_Wo, 4, 4, 4, tid, nt, F);
    fill (fbo, fin_bo, 4, tid, nt, F);
    // one-time buffers inside uni
    float* oeW0T = uni;         // 144
    float* oeb0  = uni + 144;   // 48
    float* oeWhT = uni + 192;   // 2304
    float* oebh  = uni + 2496;  // 144
    float* oeWoT = uni + 2640;  // 768
    float* oebo  = uni + 3408;  // 48
    float* aW0To = uni + 3456;  // 256
    float* ab0   = uni + 3712;  // 16
    float* rW0To = uni + 3728;  // 896
    float* objE  = uni + 4624;  // 448
    for (int s = 0; s < 3; s++){
        fillT(oeW0T + s*48, (const u16*)oe_W0 + (F?s*96:s*48), 3, 16, 16, tid, nt, F);
        for (int l = 0; l < 3; l++)
            fillT(oeWhT + (s*3+l)*256, (const u16*)oe_Wh + (F?(s*3+l)*512:(s*3+l)*256), 16, 16, 16, tid, nt, F);
        fillT(oeWoT + s*256, (const u16*)oe_Wo + (F?s*512:s*256), 16, 16, 16, tid, nt, F);
    }
    fill(oeb0, oe_b0, 48, tid, nt, F);
    fill(oebh, oe_bh, 144, tid, nt, F);
    fill(oebo, oe_bo, 48, tid, nt, F);
    fillT(aW0To, (const u16*)att_W0 + (F?512:256), 16, 16, 16, tid, nt, F);  // obj rows 16..31
    fill (ab0, att_b0, 16, tid, nt, F);
    for (int s = 0; s < 7; s++)
        fillT(rW0To + s*128, (const u16*)rel_W0 + (F?(s*512+256):(s*256+128)), 16, 8, 8, tid, nt, F);  // obj rows
    __syncthreads();

    // ---------------- phase 0b: obj embeddings (28 units) ----------------
    if (tid < 28){
        int b1 = tid / 7, s = tid % 7;
        float o[16];
        if (s < 3){
            int b = blk*4 + b1;
            float x0 = ldg(envs, b*9+3*s, F), x1 = ldg(envs, b*9+3*s+1, F), x2 = ldg(envs, b*9+3*s+2, F);
            float h[16], h2[16];
            #pragma unroll
            for (int i = 0; i < 16; i++){
                float a = oeb0[s*16+i] + x0*oeW0T[s*48+i*3] + x1*oeW0T[s*48+i*3+1] + x2*oeW0T[s*48+i*3+2];
                h[i] = elu_f(a);
            }
            for (int l = 0; l < 3; l++){
                #pragma unroll
                for (int i = 0; i < 16; i++){
                    float a = oebh[(s*3+l)*16+i];
                    #pragma unroll
                    for (int k = 0; k < 16; k++) a += h[k]*oeWhT[((s*3+l)*16+i)*16+k];
                    h2[i] = elu_f(a);
                }
                #pragma unroll
                for (int i = 0; i < 16; i++) h[i] = h2[i];
            }
            #pragma unroll
            for (int i = 0; i < 16; i++){
                float a = oebo[s*16+i];
                #pragma unroll
                for (int k = 0; k < 16; k++) a += h[k]*oeWoT[(s*16+i)*16+k];
                o[i] = a;                       // linear output layer
            }
        } else {
            #pragma unroll
            for (int i = 0; i < 16; i++) o[i] = ldg(null_embed, (s-3)*16 + i, F);
        }
        #pragma unroll
        for (int i = 0; i < 16; i++) objE[(b1*7+s)*16 + i] = o[i];
    }
    __syncthreads();

    // ---------------- phase 0c: E_att, E_rel, base_xi ----------------
    for (int idx = tid; idx < 448; idx += nt){
        int r = idx % 112, i = r % 16;
        int os = (idx / 16) * 16;
        float a = ab0[i];
        #pragma unroll
        for (int k = 0; k < 16; k++) a += objE[os + k]*aW0To[i*16+k];
        E_att[idx] = a;
    }
    for (int idx = tid; idx < 224; idx += nt){
        int r = idx % 56, s = r / 8, i = r % 8;
        int b1 = idx / 56;
        float a = ldg(rel_b0, s*8+i, F);
        #pragma unroll
        for (int k = 0; k < 16; k++) a += objE[(b1*7+s)*16 + k]*rW0To[(s*8+i)*16+k];
        E_rel[idx] = a;
    }
    for (int idx = tid; idx < 192; idx += nt){
        int b1 = idx / 48, g = idx % 48;
        float a = ldg(gru0_bi, g, F) + (g < 32 ? ldg(gru0_bh, g, F) : 0.f);
        for (int s = 0; s < 7; s++){
            int wb = g*128 + 16 + s*16;
            #pragma unroll
            for (int k = 0; k < 16; k++) a += objE[(b1*7+s)*16 + k]*ldg(gru0_Wi, wb+k, F);
        }
        base_xi[idx] = a;
    }

    // ---------------- per-lane scan weights (one wave per b, lane = gate-row) ----
    // rows ordered r0..15, z16..31, n32..47 -> lane ln directly indexes row ln.
    const int wv = tid >> 6;            // wave index = local b
    const int ln = tid & 63;            // lane in wave
    const int lj = ln & 15;             // lane's h-index
    float w0[16], wi1[16], wh1[16];
    float c0 = 0.f, c1a = 0.f, c1b = 0.f;
    if (ln < 48){
        #pragma unroll
        for (int k = 0; k < 16; k++){
            w0[k]  = ldg(gru0_Wh, ln*16+k, F);
            wi1[k] = ldg(gru1_Wi, ln*16+k, F);
            wh1[k] = ldg(gru1_Wh, ln*16+k, F);
        }
        if (ln >= 32) c0 = ldg(gru0_bh, ln, F);   // bh0_n[j], n-lanes only
        c1a = ldg(gru1_bi, ln, F);
        c1b = ldg(gru1_bh, ln, F);
    } else {
        #pragma unroll
        for (int k = 0; k < 16; k++){ w0[k] = 0.f; wi1[k] = 0.f; wh1[k] = 0.f; }
    }
    float h0[16], h1[16];
    #pragma unroll
    for (int k = 0; k < 16; k++){ h0[k] = ldg(init_h, k, F); h1[k] = ldg(init_h, 16+k, F); }
    float hp0 = ldg(init_h, lj, F);        // this lane's h_prev[j], scalar (no dyn index)
    float hp1 = ldg(init_h, 16 + lj, F);
    __syncthreads();   // one-time uni region dead -> reuse as chunk buffers

    _Float16* xi_h  = (_Float16*)uni;            // 4b x 64t x 48
    _Float16* gru_h = (_Float16*)(uni + 6144);   // 4b x 64t x 16
    _Float16* csc_h = (_Float16*)(uni + 8192);   // 4b x 7s x 64t

    const int b1p = tid >> 6, tl = tid & 63;
    const int bb = blk*4 + b1p;

    for (int c = 0; c < NCH; c++){
        const int t0 = c*TC;
        // ---------------- phase 1: xi + colsc for chunk ----------------
        {
            const int t = t0 + tl;
            int sbase = ((int)bb*TLEN + t)*4;    // states (B,T,4)
            float x0 = ldg(states, sbase+0, F), x1 = ldg(states, sbase+1, F);
            float x2 = ldg(states, sbase+2, F), x3 = ldg(states, sbase+3, F);
            float h[16], h2[16];
            #pragma unroll
            for (int i = 0; i < 16; i++){
                float a = sb0[i] + x0*sW0T[i*4] + x1*sW0T[i*4+1] + x2*sW0T[i*4+2] + x3*sW0T[i*4+3];
                h[i] = fmaxf(a, 0.f);
            }
            for (int l = 0; l < 3; l++){
                #pragma unroll
                for (int i = 0; i < 16; i++){
                    float a = sbh[l*16+i];
                    #pragma unroll
                    for (int k = 0; k < 16; k++) a += h[k]*sWhT[(l*16+i)*16+k];
                    h2[i] = fmaxf(a, 0.f);
                }
                #pragma unroll
                for (int i = 0; i < 16; i++) h[i] = h2[i];
            }
            float se[16];
            #pragma unroll
            for (int i = 0; i < 16; i++){
                float a = sbo[i];
                #pragma unroll
                for (int k = 0; k < 16; k++) a += h[k]*sWoT[i*16+k];
                se[i] = a;
            }
            float satt[16];
            #pragma unroll
            for (int i = 0; i < 16; i++){
                float a = 0.f;
                #pragma unroll
                for (int k = 0; k < 16; k++) a += se[k]*aW0T[i*16+k];
                satt[i] = a;
            }
            float sc[7];
            #pragma unroll
            for (int s = 0; s < 7; s++){          // UNROLLED: sc[] stays in VGPRs
                const float* ep = E_att + (b1p*7+s)*16;   // includes att_b0
                float a1[16], a2[16];
                #pragma unroll
                for (int i = 0; i < 16; i++) a1[i] = elu_f(satt[i] + ep[i]);
                #pragma unroll
                for (int i = 0; i < 16; i++){
                    float a = abh[i];
                    #pragma unroll
                    for (int k = 0; k < 16; k++) a += a1[k]*aWhT[i*16+k];
                    a2[i] = elu_f(a);
                }
                #pragma unroll
                for (int i = 0; i < 16; i++){
                    float a = abh[16+i];
                    #pragma unroll
                    for (int k = 0; k < 16; k++) a += a2[k]*aWhT[256 + i*16+k];
                    a1[i] = elu_f(a);
                }
                float a = abo_s[0];
                #pragma unroll
                for (int k = 0; k < 16; k++) a += a1[k]*aWo[k];
                sc[s] = a;
            }
            float m = sc[0];
            #pragma unroll
            for (int s = 1; s < 7; s++) m = fmaxf(m, sc[s]);
            float e[7], sum = 0.f;
            #pragma unroll
            for (int s = 0; s < 7; s++){ e[s] = fexp2((sc[s]-m)*LOG2E); sum += e[s]; }
            float inv = frcp(sum);
            #pragma unroll
            for (int s = 0; s < 7; s++)
                csc_h[(b1p*7+s)*64 + tl] = (_Float16)(e[6-s]*inv);   // flip+softmax
            #pragma unroll
            for (int g = 0; g < 48; g++){
                float a = base_xi[b1p*48 + g];
                #pragma unroll
                for (int k = 0; k < 16; k++) a += se[k]*wi0se[g*16+k];
                xi_h[(b1p*64 + tl)*48 + g] = (_Float16)a;
            }
        }
        __syncthreads();
        // ------- phase 2: GRU scan — wave wv handles b=blk*4+wv, lanes 0..47 -------
        for (int s = 0; s < TC; s++){
            const int slot = wv*64 + s;
            float xv = (ln < 48) ? (float)xi_h[slot*48 + ln] : 0.f;
            // layer 0: acc = w0 . h0  (4 partials to shorten dep chain)
            float p0=0.f,p1=0.f,p2=0.f,p3=0.f;
            #pragma unroll
            for (int k = 0; k < 4; k++){
                p0 += h0[k]*w0[k];       p1 += h0[4+k]*w0[4+k];
                p2 += h0[8+k]*w0[8+k];   p3 += h0[12+k]*w0[12+k];
            }
            float accb = (p0+p1)+(p2+p3) + c0;   // c0=0 on r/z lanes; = bh0_n on n lanes
            float g = sigm(xv + accb);           // r gate on lanes 0..15, z on 16..31
            float rj = __shfl(g, lj);
            float zj = __shfl(g, 16 + lj);
            float nn = tanh_f(xv + rj*accb);     // n on lanes 32..47 (xv has bi0_n)
            float hnew = (1.f - zj)*nn + zj*hp0; // meaningful on n-lanes
            hp0 = __shfl(hnew, 32 + lj);         // scalar h_prev[j] for next step
            #pragma unroll
            for (int k = 0; k < 16; k++) h0[k] = __shfl(hnew, 32+k);   // h0 <- y0
            // layer 1: a = bi1 + Wi1.h0new ; b = bh1 + Wh1.h1
            float q0=0.f,q1=0.f,q2=0.f,q3=0.f,u0=0.f,u1=0.f,u2=0.f,u3=0.f;
            #pragma unroll
            for (int k = 0; k < 4; k++){
                q0 += h0[k]*wi1[k];        u0 += h1[k]*wh1[k];
                q1 += h0[4+k]*wi1[4+k];    u1 += h1[4+k]*wh1[4+k];
                q2 += h0[8+k]*wi1[8+k];    u2 += h1[8+k]*wh1[8+k];
                q3 += h0[12+k]*wi1[12+k];  u3 += h1[12+k]*wh1[12+k];
            }
            float a = c1a + (q0+q1)+(q2+q3);
            float b = c1b + (u0+u1)+(u2+u3);
            float g1 = sigm(a + b);
            float r1 = __shfl(g1, lj);
            float z1 = __shfl(g1, 16 + lj);
            float n1 = tanh_f(a + r1*b);
            float h1new = (1.f - z1)*n1 + z1*hp1;
            hp1 = __shfl(h1new, 32 + lj);
            if (ln >= 32 && ln < 48) gru_h[slot*16 + (ln - 32)] = (_Float16)h1new;
            #pragma unroll
            for (int k = 0; k < 16; k++) h1[k] = __shfl(h1new, 32+k);
        }
        __syncthreads();
        // ---------------- phase 3: rel x7 + final MLP -> out ----------------
        {
            float g[16];
            #pragma unroll
            for (int i = 0; i < 16; i++) g[i] = (float)gru_h[(b1p*64 + tl)*16 + i];
            float wvv[56];
            #pragma unroll
            for (int s = 0; s < 7; s++){          // UNROLLED: wvv[] stays in VGPRs
                const float* ep = E_rel + (b1p*7+s)*8;   // includes rel_b0
                float p1a[8], p2a[8];
                #pragma unroll
                for (int i = 0; i < 8; i++){
                    float a = ep[i];
                    #pragma unroll
                    for (int k = 0; k < 16; k++) a += g[k]*rW0T[(s*8+i)*16+k];
                    p1a[i] = elu_f(a);
                }
                #pragma unroll
                for (int i = 0; i < 8; i++){
                    float a = rbh[s*8+i];
                    #pragma unroll
                    for (int k = 0; k < 8; k++) a += p1a[k]*rWhT[(s*8+i)*8+k];
                    p2a[i] = elu_f(a);
                }
                float w = (float)csc_h[(b1p*7+s)*64 + tl];
                #pragma unroll
                for (int i = 0; i < 8; i++){
                    float a = rbo[s*8+i];
                    #pragma unroll
                    for (int k = 0; k < 8; k++) a += p2a[k]*rWoT[(s*8+i)*8+k];
                    wvv[s*8+i] = a*w;
                }
            }
            float f1[4], f2[4], o[4];
            #pragma unroll
            for (int cc = 0; cc < 4; cc++){
                float a = fb0[cc];
                #pragma unroll
                for (int k = 0; k < 16; k++) a += g[k]*fW0T[cc*72+k];
                #pragma unroll
                for (int k = 0; k < 56; k++) a += wvv[k]*fW0T[cc*72+16+k];
                f1[cc] = elu_f(a);
            }
            #pragma unroll
            for (int cc = 0; cc < 4; cc++){
                float a = fbh[cc];
                #pragma unroll
                for (int k = 0; k < 4; k++) a += f1[k]*fWhT[cc*4+k];
                f2[cc] = elu_f(a);
            }
            #pragma unroll
            for (int cc = 0; cc < 4; cc++){
                float a = fbo[cc];
                #pragma unroll
                for (int k = 0; k < 4; k++) a += f2[k]*fWoT[cc*4+k];
                o[cc] = a;
            }
            size_t ofs = ((size_t)bb*TLEN + (t0 + tl))*4;   // out (B,T,4)
            if (F){
                float4 v; v.x = o[0]; v.y = o[1]; v.z = o[2]; v.w = o[3];
                *(float4*)((float*)out + ofs) = v;
            } else {
                u32 lo = (u32)f2bf(o[0]) | ((u32)f2bf(o[1]) << 16);
                u32 hi = (u32)f2bf(o[2]) | ((u32)f2bf(o[3]) << 16);
                *(uint2*)((u16*)out + ofs) = make_uint2(lo, hi);
            }
        }
        __syncthreads();   // protect chunk buffers before next phase 1
    }
}

extern "C" void kernel_launch(void* const* d_in, const int* in_sizes, int n_in,
                              void* d_out, int out_size, void* d_ws, size_t ws_size,
                              hipStream_t stream)
{
    (void)in_sizes; (void)n_in; (void)out_size; (void)d_ws; (void)ws_size;
    fused<<<dim3(256), dim3(256), 0, stream>>>(
        d_in[0],  d_in[1],
        d_in[2],  d_in[3],  d_in[4],  d_in[5],  d_in[6],  d_in[7],
        d_in[8],  d_in[9],  d_in[10], d_in[11], d_in[12], d_in[13],
        d_in[14], d_in[15],
        d_in[16], d_in[17], d_in[18], d_in[19], d_in[20], d_in[21],
        d_in[22], d_in[23], d_in[24], d_in[25],
        d_in[26], d_in[27], d_in[28], d_in[29],
        d_in[30], d_in[31], d_in[32], d_in[33], d_in[34], d_in[35],
        d_in[36], d_in[37], d_in[38], d_in[39], d_in[40], d_in[41],
        d_out);
}